// Round 5
// baseline (254.369 us; speedup 1.0000x reference)
//
#include <hip/hip_runtime.h>
#include <math.h>

#define DD 192
#define HH 192
#define WW 192
#define NVOX (DD*HH*WW)        // 7077888
#define NV4  (NVOX/4)          // 1769472
#define RB   1024              // reduction blocks
#define RT   256               // reduction threads per block

typedef float f32x4 __attribute__((ext_vector_type(4)));

struct Consts {
    float tx, ty, tz;          // grid translation
    float wgt[8];              // corner weights, index = dz*4+dy*2+dx
    int   dx0, dy0, dz0;       // integer corner offsets (floor of shift)
};

__device__ __forceinline__ float gcoord(int i, int n) {
    return -1.0f + (float)i * (2.0f / (float)(n - 1));
}

__device__ __forceinline__ f32x4 load4u(const float* p) {
    f32x4 v;
    __builtin_memcpy(&v, p, sizeof(v));   // 4B-aligned 16B load
    return v;
}

// Fused reduce + last-block finalize.
// quantities: 0:sum_x 1:sum x*gx 2:sum x*gy 3:sum x*gz  4..7: same for y
__global__ void reduce_kernel(const float* __restrict__ x,
                              const float* __restrict__ y,
                              double* __restrict__ partials,
                              unsigned int* __restrict__ counter,
                              Consts* __restrict__ cs) {
    double acc[8] = {0,0,0,0,0,0,0,0};
    int tid = blockIdx.x * blockDim.x + threadIdx.x;
    const float4* x4 = (const float4*)x;
    const float4* y4 = (const float4*)y;
    for (int i = tid; i < NV4; i += RB * RT) {
        float4 xv = x4[i];
        float4 yv = y4[i];
        int base = i * 4;
        int w = base % WW;          // multiple of 4
        int rem = base / WW;
        int h = rem % HH;
        int d = rem / HH;
        float gy = gcoord(h, HH);
        float gz = gcoord(d, DD);
        float xs[4] = {xv.x, xv.y, xv.z, xv.w};
        float ys[4] = {yv.x, yv.y, yv.z, yv.w};
        #pragma unroll
        for (int k = 0; k < 4; ++k) {
            float gx = gcoord(w + k, WW);
            acc[0] += (double)xs[k];
            acc[1] += (double)(xs[k] * gx);
            acc[2] += (double)(xs[k] * gy);
            acc[3] += (double)(xs[k] * gz);
            acc[4] += (double)ys[k];
            acc[5] += (double)(ys[k] * gx);
            acc[6] += (double)(ys[k] * gy);
            acc[7] += (double)(ys[k] * gz);
        }
    }
    #pragma unroll
    for (int q = 0; q < 8; ++q) {
        double v = acc[q];
        #pragma unroll
        for (int off = 32; off > 0; off >>= 1)
            v += __shfl_down(v, off, 64);
        acc[q] = v;
    }
    __shared__ double lds[4][8];
    __shared__ int is_last;
    int lane = threadIdx.x & 63;
    int wave = threadIdx.x >> 6;
    if (lane == 0) {
        #pragma unroll
        for (int q = 0; q < 8; ++q) lds[wave][q] = acc[q];
    }
    __syncthreads();
    if (threadIdx.x < 8) {
        int q = threadIdx.x;
        partials[q * RB + blockIdx.x] = lds[0][q] + lds[1][q] + lds[2][q] + lds[3][q];
    }
    // last-block-done pattern (rocPRIM-style): device-scope release then count
    __threadfence();
    if (threadIdx.x == 0) {
        unsigned int prev = atomicAdd(counter, 1u);   // device-scope by default
        is_last = (prev == RB - 1) ? 1 : 0;
    }
    __syncthreads();
    if (!is_last) return;

    // ---- finalize (runs in exactly one block, after all partials visible) ----
    __threadfence();   // acquire side
    double s[8];
    #pragma unroll
    for (int q = 0; q < 8; ++q) {
        double v = 0.0;
        for (int i = threadIdx.x; i < RB; i += RT) v += partials[q * RB + i];
        #pragma unroll
        for (int off = 32; off > 0; off >>= 1)
            v += __shfl_down(v, off, 64);
        s[q] = v;
    }
    __syncthreads();   // lds reuse
    if (lane == 0) {
        #pragma unroll
        for (int q = 0; q < 8; ++q) lds[wave][q] = s[q];
    }
    __syncthreads();
    if (threadIdx.x == 0) {
        double sums[8];
        #pragma unroll
        for (int q = 0; q < 8; ++q)
            sums[q] = lds[0][q] + lds[1][q] + lds[2][q] + lds[3][q];
        double tx = sums[1] / sums[0] - sums[5] / sums[4];
        double ty = sums[2] / sums[0] - sums[6] / sums[4];
        double tz = sums[3] / sums[0] - sums[7] / sums[4];
        Consts c;
        c.tx = (float)tx; c.ty = (float)ty; c.tz = (float)tz;
        double cx = tx * (double)(WW - 1) * 0.5;
        double cy = ty * (double)(HH - 1) * 0.5;
        double cz = tz * (double)(DD - 1) * 0.5;
        double fx = floor(cx), fy = floor(cy), fz = floor(cz);
        float wx = (float)(cx - fx), wy = (float)(cy - fy), wz = (float)(cz - fz);
        c.dx0 = (int)fx; c.dy0 = (int)fy; c.dz0 = (int)fz;
        #pragma unroll
        for (int k = 0; k < 8; ++k) {
            float wzz = (k & 4) ? wz : 1.0f - wz;
            float wyy = (k & 2) ? wy : 1.0f - wy;
            float wxx = (k & 1) ? wx : 1.0f - wx;
            c.wgt[k] = wzz * wyy * wxx;
        }
        *cs = c;   // visible to main_kernel via kernel-boundary flush
    }
}

// Fused main: 4 voxels/thread (1024 voxels/block).
// Grid: 12 floats/thread staged in LDS, stored as 3 lane-consecutive float4
// NT stores (full-line write-back). Trilinear: constant-shift stencil.
__global__ void __launch_bounds__(256) main_kernel(const float* __restrict__ x,
                                                   const Consts* __restrict__ csp,
                                                   f32x4* __restrict__ out_t4,
                                                   f32x4* __restrict__ out_g4) {
    __shared__ float gbuf[3072];           // 1024 voxels * 3 comps = 12 KB
    const Consts c = *csp;                 // uniform address -> scalar loads
    int t = blockIdx.x * 256 + threadIdx.x; // group of 4 voxels (row-aligned)
    int vb = t * 4;
    int w0 = vb % WW;
    int rem = vb / WW;
    int h = rem % HH;
    int d = rem / HH;

    float gx0 = gcoord(w0 + 0, WW) + c.tx;
    float gx1 = gcoord(w0 + 1, WW) + c.tx;
    float gx2 = gcoord(w0 + 2, WW) + c.tx;
    float gx3 = gcoord(w0 + 3, WW) + c.tx;
    float gy  = gcoord(h, HH) + c.ty;
    float gz  = gcoord(d, DD) + c.tz;
    {
        f32x4* myg = (f32x4*)&gbuf[threadIdx.x * 12];
        f32x4 f0 = {gx0, gy, gz, gx1};
        f32x4 f1 = {gy, gz, gx2, gy};
        f32x4 f2 = {gz, gx3, gy, gz};
        myg[0] = f0; myg[1] = f1; myg[2] = f2;
    }

    int yi0 = h + c.dy0, yi1 = yi0 + 1;
    int zi0 = d + c.dz0, zi1 = zi0 + 1;
    int ys0 = min(max(yi0, 0), HH - 1), ys1 = min(max(yi1, 0), HH - 1);
    int zs0 = min(max(zi0, 0), DD - 1), zs1 = min(max(zi1, 0), DD - 1);
    float vy0 = ((unsigned)yi0 < (unsigned)HH) ? 1.0f : 0.0f;
    float vy1 = ((unsigned)yi1 < (unsigned)HH) ? 1.0f : 0.0f;
    float vz0 = ((unsigned)zi0 < (unsigned)DD) ? 1.0f : 0.0f;
    float vz1 = ((unsigned)zi1 < (unsigned)DD) ? 1.0f : 0.0f;
    int   rb[4]  = { (zs0 * HH + ys0) * WW, (zs0 * HH + ys1) * WW,
                     (zs1 * HH + ys0) * WW, (zs1 * HH + ys1) * WW };
    float sr[4]  = { vz0 * vy0, vz0 * vy1, vz1 * vy0, vz1 * vy1 };

    int xi0g = w0 + c.dx0;
    f32x4 acc = {0.0f, 0.0f, 0.0f, 0.0f};

    if (xi0g >= 0 && xi0g + 4 <= WW - 1) {
        #pragma unroll
        for (int r = 0; r < 4; ++r) {
            float w0r = sr[r] * c.wgt[2 * r + 0];
            float w1r = sr[r] * c.wgt[2 * r + 1];
            const float* p = x + rb[r] + xi0g;
            f32x4 v  = load4u(p);
            float v4 = p[4];
            acc.x += w0r * v.x + w1r * v.y;
            acc.y += w0r * v.y + w1r * v.z;
            acc.z += w0r * v.z + w1r * v.w;
            acc.w += w0r * v.w + w1r * v4;
        }
    } else {
        float res[4];
        #pragma unroll
        for (int k = 0; k < 4; ++k) {
            int xi0 = xi0g + k, xi1 = xi0 + 1;
            int xs0 = min(max(xi0, 0), WW - 1), xs1 = min(max(xi1, 0), WW - 1);
            float vx0 = ((unsigned)xi0 < (unsigned)WW) ? 1.0f : 0.0f;
            float vx1 = ((unsigned)xi1 < (unsigned)WW) ? 1.0f : 0.0f;
            float a = 0.0f;
            #pragma unroll
            for (int r = 0; r < 4; ++r) {
                a += x[rb[r] + xs0] * (sr[r] * c.wgt[2 * r + 0] * vx0);
                a += x[rb[r] + xs1] * (sr[r] * c.wgt[2 * r + 1] * vx1);
            }
            res[k] = a;
        }
        acc.x = res[0]; acc.y = res[1]; acc.z = res[2]; acc.w = res[3];
    }
    __builtin_nontemporal_store(acc, &out_t4[t]);

    __syncthreads();
    const f32x4* gsrc = (const f32x4*)gbuf;
    int gbase = blockIdx.x * 768;
    #pragma unroll
    for (int k = 0; k < 3; ++k) {
        int p = k * 256 + threadIdx.x;
        __builtin_nontemporal_store(gsrc[p], &out_g4[gbase + p]);
    }
}

extern "C" void kernel_launch(void* const* d_in, const int* in_sizes, int n_in,
                              void* d_out, int out_size, void* d_ws, size_t ws_size,
                              hipStream_t stream) {
    const float* x = (const float*)d_in[0];
    const float* y = (const float*)d_in[1];
    float* out = (float*)d_out;
    f32x4* out_t4 = (f32x4*)out;              // transformed: NVOX floats
    f32x4* out_g4 = (f32x4*)(out + NVOX);     // grid: NVOX*3 floats
    double* partials = (double*)d_ws;         // 8*RB doubles = 64 KiB
    Consts* cs = (Consts*)((char*)d_ws + 8 * RB * sizeof(double));
    unsigned int* counter = (unsigned int*)((char*)d_ws + 8 * RB * sizeof(double) + 256);
    // ws is poisoned 0xAA before every call — zero the done-counter (async, capture-legal)
    hipMemsetAsync(counter, 0, sizeof(unsigned int), stream);
    reduce_kernel<<<RB, RT, 0, stream>>>(x, y, partials, counter, cs);
    main_kernel<<<NVOX / 4 / 256, 256, 0, stream>>>(x, cs, out_t4, out_g4);
}

// Round 6
// 180.578 us; speedup vs baseline: 1.4086x; 1.4086x over previous
//
#include <hip/hip_runtime.h>
#include <math.h>

#define DD 192
#define HH 192
#define WW 192
#define NVOX (DD*HH*WW)        // 7077888
#define NV4  (NVOX/4)          // 1769472
#define RB   512               // reduction blocks
#define RT   256               // threads per block (both kernels)

typedef float f32x4 __attribute__((ext_vector_type(4)));

struct Consts {
    float tx, ty, tz;          // grid translation
    float wgt[8];              // corner weights, index = r*2+dx (r = dz*2+dy)
    int   dx0, dy0, dz0;       // integer corner offsets (floor of shift)
};

__device__ __forceinline__ float gcoord(int i, int n) {
    return -1.0f + (float)i * (2.0f / (float)(n - 1));
}

__device__ __forceinline__ f32x4 load4u(const float* p) {
    f32x4 v;
    __builtin_memcpy(&v, p, sizeof(v));   // 4B-aligned 16B load
    return v;
}

// quantities: 0:sum_x 1:sum x*gx 2:sum x*gy 3:sum x*gz  4..7: same for y
// Deterministic per-block partials; NO fences/atomics (kernel boundary = publish).
__global__ void __launch_bounds__(RT) reduce_kernel(const float* __restrict__ x,
                                                    const float* __restrict__ y,
                                                    double* __restrict__ partials) {
    double acc[8] = {0,0,0,0,0,0,0,0};
    int tid = blockIdx.x * RT + threadIdx.x;
    const float4* x4 = (const float4*)x;
    const float4* y4 = (const float4*)y;
    for (int i = tid; i < NV4; i += RB * RT) {
        float4 xv = x4[i];
        float4 yv = y4[i];
        int base = i * 4;
        int w = base % WW;          // multiple of 4
        int rem = base / WW;
        int h = rem % HH;
        int d = rem / HH;
        float gy = gcoord(h, HH);
        float gz = gcoord(d, DD);
        float xs[4] = {xv.x, xv.y, xv.z, xv.w};
        float ys[4] = {yv.x, yv.y, yv.z, yv.w};
        #pragma unroll
        for (int k = 0; k < 4; ++k) {
            float gx = gcoord(w + k, WW);
            acc[0] += (double)xs[k];
            acc[1] += (double)(xs[k] * gx);
            acc[2] += (double)(xs[k] * gy);
            acc[3] += (double)(xs[k] * gz);
            acc[4] += (double)ys[k];
            acc[5] += (double)(ys[k] * gx);
            acc[6] += (double)(ys[k] * gy);
            acc[7] += (double)(ys[k] * gz);
        }
    }
    #pragma unroll
    for (int q = 0; q < 8; ++q) {
        double v = acc[q];
        #pragma unroll
        for (int off = 32; off > 0; off >>= 1)
            v += __shfl_down(v, off, 64);
        acc[q] = v;
    }
    __shared__ double lds[4][8];
    int lane = threadIdx.x & 63;
    int wave = threadIdx.x >> 6;
    if (lane == 0) {
        #pragma unroll
        for (int q = 0; q < 8; ++q) lds[wave][q] = acc[q];
    }
    __syncthreads();
    if (threadIdx.x < 8) {
        int q = threadIdx.x;
        partials[q * RB + blockIdx.x] = lds[0][q] + lds[1][q] + lds[2][q] + lds[3][q];
    }
}

// Fused main: per-block prologue re-reduces the 8x512 partials (32 KB,
// L2-resident) into Consts — removes the separate finalize dispatch with no
// fences. Then 4 voxels/thread: grid staged in LDS -> 3 lane-consecutive
// float4 NT stores (full-line writeback); trilinear = constant-shift stencil.
__global__ void __launch_bounds__(RT) main_kernel(const float* __restrict__ x,
                                                  const double* __restrict__ partials,
                                                  f32x4* __restrict__ out_t4,
                                                  f32x4* __restrict__ out_g4) {
    __shared__ float gbuf[3072];           // 1024 voxels * 3 comps = 12 KB
    __shared__ Consts csh;
    {
        __shared__ double lds8[4][8];
        int lane = threadIdx.x & 63;
        int wave = threadIdx.x >> 6;
        double s[8];
        #pragma unroll
        for (int q = 0; q < 8; ++q) {
            double v = partials[q * RB + threadIdx.x]
                     + partials[q * RB + RT + threadIdx.x];   // RB = 2*RT
            #pragma unroll
            for (int off = 32; off > 0; off >>= 1)
                v += __shfl_down(v, off, 64);
            s[q] = v;
        }
        if (lane == 0) {
            #pragma unroll
            for (int q = 0; q < 8; ++q) lds8[wave][q] = s[q];
        }
        __syncthreads();
        if (threadIdx.x == 0) {
            double sums[8];
            #pragma unroll
            for (int q = 0; q < 8; ++q)
                sums[q] = lds8[0][q] + lds8[1][q] + lds8[2][q] + lds8[3][q];
            double tx = sums[1] / sums[0] - sums[5] / sums[4];
            double ty = sums[2] / sums[0] - sums[6] / sums[4];
            double tz = sums[3] / sums[0] - sums[7] / sums[4];
            csh.tx = (float)tx; csh.ty = (float)ty; csh.tz = (float)tz;
            double cx = tx * (double)(WW - 1) * 0.5;
            double cy = ty * (double)(HH - 1) * 0.5;
            double cz = tz * (double)(DD - 1) * 0.5;
            double fx = floor(cx), fy = floor(cy), fz = floor(cz);
            float wx = (float)(cx - fx), wy = (float)(cy - fy), wz = (float)(cz - fz);
            csh.dx0 = (int)fx; csh.dy0 = (int)fy; csh.dz0 = (int)fz;
            #pragma unroll
            for (int k = 0; k < 8; ++k) {
                float wzz = (k & 4) ? wz : 1.0f - wz;
                float wyy = (k & 2) ? wy : 1.0f - wy;
                float wxx = (k & 1) ? wx : 1.0f - wx;
                csh.wgt[k] = wzz * wyy * wxx;
            }
        }
        __syncthreads();
    }
    const Consts c = csh;

    int t = blockIdx.x * RT + threadIdx.x;  // group of 4 voxels (row-aligned)
    int vb = t * 4;
    int w0 = vb % WW;
    int rem = vb / WW;
    int h = rem % HH;
    int d = rem / HH;

    float gx0 = gcoord(w0 + 0, WW) + c.tx;
    float gx1 = gcoord(w0 + 1, WW) + c.tx;
    float gx2 = gcoord(w0 + 2, WW) + c.tx;
    float gx3 = gcoord(w0 + 3, WW) + c.tx;
    float gy  = gcoord(h, HH) + c.ty;
    float gz  = gcoord(d, DD) + c.tz;
    {
        f32x4* myg = (f32x4*)&gbuf[threadIdx.x * 12];
        f32x4 f0 = {gx0, gy, gz, gx1};
        f32x4 f1 = {gy, gz, gx2, gy};
        f32x4 f2 = {gz, gx3, gy, gz};
        myg[0] = f0; myg[1] = f1; myg[2] = f2;
    }

    int yi0 = h + c.dy0, yi1 = yi0 + 1;
    int zi0 = d + c.dz0, zi1 = zi0 + 1;
    int ys0 = min(max(yi0, 0), HH - 1), ys1 = min(max(yi1, 0), HH - 1);
    int zs0 = min(max(zi0, 0), DD - 1), zs1 = min(max(zi1, 0), DD - 1);
    float vy0 = ((unsigned)yi0 < (unsigned)HH) ? 1.0f : 0.0f;
    float vy1 = ((unsigned)yi1 < (unsigned)HH) ? 1.0f : 0.0f;
    float vz0 = ((unsigned)zi0 < (unsigned)DD) ? 1.0f : 0.0f;
    float vz1 = ((unsigned)zi1 < (unsigned)DD) ? 1.0f : 0.0f;
    int   rb[4]  = { (zs0 * HH + ys0) * WW, (zs0 * HH + ys1) * WW,
                     (zs1 * HH + ys0) * WW, (zs1 * HH + ys1) * WW };
    float sr[4]  = { vz0 * vy0, vz0 * vy1, vz1 * vy0, vz1 * vy1 };

    int xi0g = w0 + c.dx0;
    f32x4 acc = {0.0f, 0.0f, 0.0f, 0.0f};

    if (xi0g >= 0 && xi0g + 4 <= WW - 1) {
        // fast path: all 5 x-positions in range
        #pragma unroll
        for (int r = 0; r < 4; ++r) {
            float w0r = sr[r] * c.wgt[2 * r + 0];
            float w1r = sr[r] * c.wgt[2 * r + 1];
            const float* p = x + rb[r] + xi0g;
            f32x4 v  = load4u(p);
            float v4 = p[4];
            acc.x += w0r * v.x + w1r * v.y;
            acc.y += w0r * v.y + w1r * v.z;
            acc.z += w0r * v.z + w1r * v.w;
            acc.w += w0r * v.w + w1r * v4;
        }
    } else {
        // slow path: x-boundary groups
        float res[4];
        #pragma unroll
        for (int k = 0; k < 4; ++k) {
            int xi0 = xi0g + k, xi1 = xi0 + 1;
            int xs0 = min(max(xi0, 0), WW - 1), xs1 = min(max(xi1, 0), WW - 1);
            float vx0 = ((unsigned)xi0 < (unsigned)WW) ? 1.0f : 0.0f;
            float vx1 = ((unsigned)xi1 < (unsigned)WW) ? 1.0f : 0.0f;
            float a = 0.0f;
            #pragma unroll
            for (int r = 0; r < 4; ++r) {
                a += x[rb[r] + xs0] * (sr[r] * c.wgt[2 * r + 0] * vx0);
                a += x[rb[r] + xs1] * (sr[r] * c.wgt[2 * r + 1] * vx1);
            }
            res[k] = a;
        }
        acc.x = res[0]; acc.y = res[1]; acc.z = res[2]; acc.w = res[3];
    }
    __builtin_nontemporal_store(acc, &out_t4[t]);

    // coalesced grid store: 3 x (lanes x 16B contiguous) = full lines
    __syncthreads();
    const f32x4* gsrc = (const f32x4*)gbuf;
    int gbase = blockIdx.x * 768;
    #pragma unroll
    for (int k = 0; k < 3; ++k) {
        int p = k * 256 + threadIdx.x;
        __builtin_nontemporal_store(gsrc[p], &out_g4[gbase + p]);
    }
}

extern "C" void kernel_launch(void* const* d_in, const int* in_sizes, int n_in,
                              void* d_out, int out_size, void* d_ws, size_t ws_size,
                              hipStream_t stream) {
    const float* x = (const float*)d_in[0];
    const float* y = (const float*)d_in[1];
    float* out = (float*)d_out;
    f32x4* out_t4 = (f32x4*)out;              // transformed: NVOX floats
    f32x4* out_g4 = (f32x4*)(out + NVOX);     // grid: NVOX*3 floats
    double* partials = (double*)d_ws;         // 8*RB doubles = 32 KiB
    reduce_kernel<<<RB, RT, 0, stream>>>(x, y, partials);
    main_kernel<<<NVOX / 4 / RT, RT, 0, stream>>>(x, partials, out_t4, out_g4);
}

// Round 7
// 177.085 us; speedup vs baseline: 1.4364x; 1.0197x over previous
//
#include <hip/hip_runtime.h>
#include <math.h>

#define DD 192
#define HH 192
#define WW 192
#define NVOX (DD*HH*WW)        // 7077888
#define NV4  (NVOX/4)          // 1769472
#define RB   512               // reduction blocks
#define RT   256               // threads per block (both kernels)

typedef float f32x4 __attribute__((ext_vector_type(4)));

__device__ __forceinline__ float gcoord(int i, int n) {
    return -1.0f + (float)i * (2.0f / (float)(n - 1));
}

__device__ __forceinline__ f32x4 load4u(const float* p) {
    f32x4 v;
    __builtin_memcpy(&v, p, sizeof(v));   // 4B-aligned 16B load
    return v;
}

// quantities: 0:sum_x 1:sum x*gx 2:sum x*gy 3:sum x*gz  4..7: same for y
// Deterministic per-block partials; NO fences/atomics (kernel boundary = publish).
__global__ void __launch_bounds__(RT) reduce_kernel(const float* __restrict__ x,
                                                    const float* __restrict__ y,
                                                    double* __restrict__ partials) {
    double acc[8] = {0,0,0,0,0,0,0,0};
    int tid = blockIdx.x * RT + threadIdx.x;
    const float4* x4 = (const float4*)x;
    const float4* y4 = (const float4*)y;
    for (int i = tid; i < NV4; i += RB * RT) {
        float4 xv = x4[i];
        float4 yv = y4[i];
        int base = i * 4;
        int w = base % WW;          // multiple of 4
        int rem = base / WW;
        int h = rem % HH;
        int d = rem / HH;
        float gy = gcoord(h, HH);
        float gz = gcoord(d, DD);
        float xs[4] = {xv.x, xv.y, xv.z, xv.w};
        float ys[4] = {yv.x, yv.y, yv.z, yv.w};
        #pragma unroll
        for (int k = 0; k < 4; ++k) {
            float gx = gcoord(w + k, WW);
            acc[0] += (double)xs[k];
            acc[1] += (double)(xs[k] * gx);
            acc[2] += (double)(xs[k] * gy);
            acc[3] += (double)(xs[k] * gz);
            acc[4] += (double)ys[k];
            acc[5] += (double)(ys[k] * gx);
            acc[6] += (double)(ys[k] * gy);
            acc[7] += (double)(ys[k] * gz);
        }
    }
    #pragma unroll
    for (int q = 0; q < 8; ++q) {
        double v = acc[q];
        #pragma unroll
        for (int off = 32; off > 0; off >>= 1)
            v += __shfl_down(v, off, 64);
        acc[q] = v;
    }
    __shared__ double lds[4][8];
    int lane = threadIdx.x & 63;
    int wave = threadIdx.x >> 6;
    if (lane == 0) {
        #pragma unroll
        for (int q = 0; q < 8; ++q) lds[wave][q] = acc[q];
    }
    __syncthreads();
    if (threadIdx.x < 8) {
        int q = threadIdx.x;
        partials[q * RB + blockIdx.x] = lds[0][q] + lds[1][q] + lds[2][q] + lds[3][q];
    }
}

// Fused main. Per-block prologue re-reduces the 8x512 partials (32 KB,
// L2/L3-resident) into consts. Grid output is ANALYTIC: each lane computes
// the 4 floats of its own coalesced float4 slot directly (no LDS round-trip,
// no barrier, no bank conflicts). Trilinear = constant-shift stencil.
__global__ void __launch_bounds__(RT) main_kernel(const float* __restrict__ x,
                                                  const double* __restrict__ partials,
                                                  f32x4* __restrict__ out_t4,
                                                  f32x4* __restrict__ out_g4) {
    __shared__ float cw[8];       // corner weights
    __shared__ float ct[3];       // tx, ty, tz
    __shared__ int   cd[3];       // dx0, dy0, dz0
    {
        __shared__ double lds8[4][8];
        int lane = threadIdx.x & 63;
        int wave = threadIdx.x >> 6;
        double s[8];
        #pragma unroll
        for (int q = 0; q < 8; ++q) {
            double v = partials[q * RB + threadIdx.x]
                     + partials[q * RB + RT + threadIdx.x];   // RB = 2*RT
            #pragma unroll
            for (int off = 32; off > 0; off >>= 1)
                v += __shfl_down(v, off, 64);
            s[q] = v;
        }
        if (lane == 0) {
            #pragma unroll
            for (int q = 0; q < 8; ++q) lds8[wave][q] = s[q];
        }
        __syncthreads();
        if (threadIdx.x == 0) {
            double sums[8];
            #pragma unroll
            for (int q = 0; q < 8; ++q)
                sums[q] = lds8[0][q] + lds8[1][q] + lds8[2][q] + lds8[3][q];
            double rx = 1.0 / sums[0], ry = 1.0 / sums[4];    // 2 divides, not 6
            double tx = sums[1] * rx - sums[5] * ry;
            double ty = sums[2] * rx - sums[6] * ry;
            double tz = sums[3] * rx - sums[7] * ry;
            ct[0] = (float)tx; ct[1] = (float)ty; ct[2] = (float)tz;
            double cx = tx * (double)(WW - 1) * 0.5;
            double cy = ty * (double)(HH - 1) * 0.5;
            double cz = tz * (double)(DD - 1) * 0.5;
            double fx = floor(cx), fy = floor(cy), fz = floor(cz);
            float wx = (float)(cx - fx), wy = (float)(cy - fy), wz = (float)(cz - fz);
            cd[0] = (int)fx; cd[1] = (int)fy; cd[2] = (int)fz;
            #pragma unroll
            for (int k = 0; k < 8; ++k) {
                float wzz = (k & 4) ? wz : 1.0f - wz;
                float wyy = (k & 2) ? wy : 1.0f - wy;
                float wxx = (k & 1) ? wx : 1.0f - wx;
                cw[k] = wzz * wyy * wxx;
            }
        }
        __syncthreads();
    }
    const float tx = ct[0], ty = ct[1], tz = ct[2];
    const int dx0 = cd[0], dy0 = cd[1], dz0 = cd[2];

    int t = blockIdx.x * RT + threadIdx.x;  // group of 4 voxels (row-aligned)
    int vb = t * 4;
    int w0 = vb % WW;
    int rem = vb / WW;
    int h = rem % HH;
    int d = rem / HH;

    // ---- analytic grid stores: 3 coalesced float4 per thread ----
    // float index f = r*576 + w*3 + c, r = d*HH + h. 576 % 4 == 0 so each
    // float4 chunk lies in one (d,h) row and spans w0g..w0g+1 only.
    {
        int gbase = blockIdx.x * (RT * 3);
        #pragma unroll
        for (int k = 0; k < 3; ++k) {
            int p  = gbase + k * RT + threadIdx.x;   // float4 slot
            int f0 = p * 4;
            int r  = f0 / 576;
            int ro = f0 - r * 576;
            int wg = ro / 3;
            int cg = ro - wg * 3;
            int hg = r % HH;
            int dg = r / HH;
            float gxv0 = gcoord(wg,     WW) + tx;
            float gxv1 = gcoord(wg + 1, WW) + tx;
            float gyv  = gcoord(hg, HH) + ty;
            float gzv  = gcoord(dg, DD) + tz;
            float comp[4];
            #pragma unroll
            for (int j = 0; j < 4; ++j) {
                int cc = cg + j;                      // 0..5
                int c  = (cc >= 3) ? cc - 3 : cc;
                float gxv = (cc >= 3) ? gxv1 : gxv0;
                comp[j] = (c == 0) ? gxv : ((c == 1) ? gyv : gzv);
            }
            f32x4 v = {comp[0], comp[1], comp[2], comp[3]};
            __builtin_nontemporal_store(v, &out_g4[p]);
        }
    }

    // ---- trilinear: constant-shift stencil, 4 voxels/thread ----
    int yi0 = h + dy0, yi1 = yi0 + 1;
    int zi0 = d + dz0, zi1 = zi0 + 1;
    int ys0 = min(max(yi0, 0), HH - 1), ys1 = min(max(yi1, 0), HH - 1);
    int zs0 = min(max(zi0, 0), DD - 1), zs1 = min(max(zi1, 0), DD - 1);
    float vy0 = ((unsigned)yi0 < (unsigned)HH) ? 1.0f : 0.0f;
    float vy1 = ((unsigned)yi1 < (unsigned)HH) ? 1.0f : 0.0f;
    float vz0 = ((unsigned)zi0 < (unsigned)DD) ? 1.0f : 0.0f;
    float vz1 = ((unsigned)zi1 < (unsigned)DD) ? 1.0f : 0.0f;
    int   rb[4]  = { (zs0 * HH + ys0) * WW, (zs0 * HH + ys1) * WW,
                     (zs1 * HH + ys0) * WW, (zs1 * HH + ys1) * WW };
    float sr[4]  = { vz0 * vy0, vz0 * vy1, vz1 * vy0, vz1 * vy1 };

    int xi0g = w0 + dx0;
    f32x4 acc = {0.0f, 0.0f, 0.0f, 0.0f};

    if (xi0g >= 0 && xi0g + 4 <= WW - 1) {
        // fast path: all 5 x-positions in range
        #pragma unroll
        for (int r = 0; r < 4; ++r) {
            float w0r = sr[r] * cw[2 * r + 0];
            float w1r = sr[r] * cw[2 * r + 1];
            const float* p = x + rb[r] + xi0g;
            f32x4 v  = load4u(p);
            float v4 = p[4];
            acc.x += w0r * v.x + w1r * v.y;
            acc.y += w0r * v.y + w1r * v.z;
            acc.z += w0r * v.z + w1r * v.w;
            acc.w += w0r * v.w + w1r * v4;
        }
    } else {
        // slow path: x-boundary groups
        float res[4];
        #pragma unroll
        for (int k = 0; k < 4; ++k) {
            int xi0 = xi0g + k, xi1 = xi0 + 1;
            int xs0 = min(max(xi0, 0), WW - 1), xs1 = min(max(xi1, 0), WW - 1);
            float vx0 = ((unsigned)xi0 < (unsigned)WW) ? 1.0f : 0.0f;
            float vx1 = ((unsigned)xi1 < (unsigned)WW) ? 1.0f : 0.0f;
            float a = 0.0f;
            #pragma unroll
            for (int r = 0; r < 4; ++r) {
                a += x[rb[r] + xs0] * (sr[r] * cw[2 * r + 0] * vx0);
                a += x[rb[r] + xs1] * (sr[r] * cw[2 * r + 1] * vx1);
            }
            res[k] = a;
        }
        acc.x = res[0]; acc.y = res[1]; acc.z = res[2]; acc.w = res[3];
    }
    __builtin_nontemporal_store(acc, &out_t4[t]);
}

extern "C" void kernel_launch(void* const* d_in, const int* in_sizes, int n_in,
                              void* d_out, int out_size, void* d_ws, size_t ws_size,
                              hipStream_t stream) {
    const float* x = (const float*)d_in[0];
    const float* y = (const float*)d_in[1];
    float* out = (float*)d_out;
    f32x4* out_t4 = (f32x4*)out;              // transformed: NVOX floats
    f32x4* out_g4 = (f32x4*)(out + NVOX);     // grid: NVOX*3 floats
    double* partials = (double*)d_ws;         // 8*RB doubles = 32 KiB
    reduce_kernel<<<RB, RT, 0, stream>>>(x, y, partials);
    main_kernel<<<NVOX / 4 / RT, RT, 0, stream>>>(x, partials, out_t4, out_g4);
}